// Round 1
// baseline (193.275 us; speedup 1.0000x reference)
//
#include <hip/hip_runtime.h>
#include <math.h>

#define M_DIM 24
#define N_DIM 12
#define H1    2880
#define HID   7200
#define H2    1152
#define DOUT  288

// workspace layout (float offsets)
#define WS_PRIOR 0      // [24]
#define WS_KGIN  32     // [36]
#define WS_DY    96     // [12]
#define WS_L1    128    // [2880]
#define WS_HNEW  3072   // [7200]
#define WS_L2    10304  // [1152]
#define WS_KG    11520  // [288]

__device__ __forceinline__ float wave_sum(float v) {
    #pragma unroll
    for (int o = 32; o; o >>= 1) v += __shfl_xor(v, o);
    return v;
}

// ---- kernel 1: prior, m1y, normalizations, kg_in, dy ----
__global__ void k_head(const float* __restrict__ yt, const float* __restrict__ F,
                       const float* __restrict__ Hm, const float* __restrict__ post,
                       const float* __restrict__ prior_old, float* __restrict__ ws) {
    __shared__ float s_prior[M_DIM];
    __shared__ float s_m1y[N_DIM];
    int t = threadIdx.x;  // 64 threads, 1 wave
    if (t < M_DIM) {
        float acc = 0.f;
        #pragma unroll
        for (int j = 0; j < M_DIM; ++j) acc += F[t * M_DIM + j] * post[j];
        s_prior[t] = acc;
    }
    __syncthreads();
    if (t < N_DIM) {
        float acc = 0.f;
        #pragma unroll
        for (int j = 0; j < M_DIM; ++j) acc += Hm[t * M_DIM + j] * s_prior[j];
        s_m1y[t] = acc;
    }
    __syncthreads();
    float vx = 0.f;
    if (t < M_DIM) vx = post[t] - prior_old[t];
    float nx = fmaxf(sqrtf(wave_sum(vx * vx)), 1e-12f);
    float vy = 0.f;
    if (t < N_DIM) vy = yt[t] - s_m1y[t];
    float ny = fmaxf(sqrtf(wave_sum(vy * vy)), 1e-12f);
    if (t < N_DIM) ws[WS_KGIN + t] = vy / ny;               // dm1y
    if (t < M_DIM) ws[WS_KGIN + N_DIM + t] = vx / nx;       // dm1x
    if (t < M_DIM) ws[WS_PRIOR + t] = s_prior[t];
    if (t < N_DIM) ws[WS_DY + t] = vy;                      // dy = yt - m1y
}

// ---- kernel 2: l1 = relu(W1 @ kg_in + b1), wave per row ----
__global__ __launch_bounds__(256) void k_l1(const float* __restrict__ W1,
                                            const float* __restrict__ b1,
                                            float* __restrict__ ws) {
    __shared__ float s_x[M_DIM + N_DIM];
    int t = threadIdx.x, lane = t & 63, w = t >> 6;
    if (t < M_DIM + N_DIM) s_x[t] = ws[WS_KGIN + t];
    __syncthreads();
    int i = blockIdx.x * 4 + w;
    float acc = (lane < M_DIM + N_DIM)
              ? W1[(size_t)i * (M_DIM + N_DIM) + lane] * s_x[lane] : 0.f;
    acc = wave_sum(acc);
    if (lane == 0) ws[WS_L1 + i] = fmaxf(acc + b1[i], 0.f);
}

// ---- kernel 3: GRU cell, one wave per output element ----
__global__ __launch_bounds__(256) void k_gru(const float* __restrict__ Wih,
                                             const float* __restrict__ Whh,
                                             const float* __restrict__ bih,
                                             const float* __restrict__ bhh,
                                             const float* __restrict__ hn,
                                             float* __restrict__ ws) {
    __shared__ float s_l1[H1];
    __shared__ float s_h[HID];
    int t = threadIdx.x;
    float4* s_l14 = (float4*)s_l1;
    float4* s_h4  = (float4*)s_h;
    const float4* l14 = (const float4*)(ws + WS_L1);
    const float4* h4  = (const float4*)hn;
    for (int k = t; k < H1 / 4; k += 256)  s_l14[k] = l14[k];
    for (int k = t; k < HID / 4; k += 256) s_h4[k]  = h4[k];
    __syncthreads();

    int lane = t & 63, w = t >> 6;
    int i = blockIdx.x * 4 + w;

    const float4* wr = (const float4*)(Wih + (size_t)i * H1);
    const float4* wz = (const float4*)(Wih + (size_t)(i + HID) * H1);
    const float4* wn = (const float4*)(Wih + (size_t)(i + 2 * HID) * H1);
    float ar = 0.f, az = 0.f, an = 0.f;
    for (int k = lane; k < H1 / 4; k += 64) {
        float4 x = s_l14[k];
        float4 a = wr[k], b = wz[k], c = wn[k];
        ar += a.x * x.x + a.y * x.y + a.z * x.z + a.w * x.w;
        az += b.x * x.x + b.y * x.y + b.z * x.z + b.w * x.w;
        an += c.x * x.x + c.y * x.y + c.z * x.z + c.w * x.w;
    }

    const float4* ur = (const float4*)(Whh + (size_t)i * HID);
    const float4* uz = (const float4*)(Whh + (size_t)(i + HID) * HID);
    const float4* un = (const float4*)(Whh + (size_t)(i + 2 * HID) * HID);
    float hr = 0.f, hz = 0.f, hh = 0.f;
    for (int k = lane; k < HID / 4; k += 64) {
        float4 x = s_h4[k];
        float4 a = ur[k], b = uz[k], c = un[k];
        hr += a.x * x.x + a.y * x.y + a.z * x.z + a.w * x.w;
        hz += b.x * x.x + b.y * x.y + b.z * x.z + b.w * x.w;
        hh += c.x * x.x + c.y * x.y + c.z * x.z + c.w * x.w;
    }

    ar = wave_sum(ar); az = wave_sum(az); an = wave_sum(an);
    hr = wave_sum(hr); hz = wave_sum(hz); hh = wave_sum(hh);

    if (lane == 0) {
        float gr = ar + bih[i] + hr + bhh[i];
        float gz = az + bih[i + HID] + hz + bhh[i + HID];
        float r = 1.f / (1.f + expf(-gr));
        float z = 1.f / (1.f + expf(-gz));
        float n = tanhf(an + bih[i + 2 * HID] + r * (hh + bhh[i + 2 * HID]));
        ws[WS_HNEW + i] = (1.f - z) * n + z * s_h[i];
    }
}

// ---- kernel 4: l2 = relu(W2 @ h_new + b2), wave per row ----
__global__ __launch_bounds__(256) void k_l2(const float* __restrict__ W2,
                                            const float* __restrict__ b2,
                                            float* __restrict__ ws) {
    __shared__ float s_h[HID];
    int t = threadIdx.x;
    float4* s_h4 = (float4*)s_h;
    const float4* h4 = (const float4*)(ws + WS_HNEW);
    for (int k = t; k < HID / 4; k += 256) s_h4[k] = h4[k];
    __syncthreads();
    int lane = t & 63, w = t >> 6;
    int i = blockIdx.x * 4 + w;
    const float4* wr = (const float4*)(W2 + (size_t)i * HID);
    float acc = 0.f;
    for (int k = lane; k < HID / 4; k += 64) {
        float4 x = s_h4[k];
        float4 a = wr[k];
        acc += a.x * x.x + a.y * x.y + a.z * x.z + a.w * x.w;
    }
    acc = wave_sum(acc);
    if (lane == 0) ws[WS_L2 + i] = fmaxf(acc + b2[i], 0.f);
}

// ---- kernel 5: kg = W3 @ l2 + b3, wave per row ----
__global__ __launch_bounds__(256) void k_kg(const float* __restrict__ W3,
                                            const float* __restrict__ b3,
                                            float* __restrict__ ws) {
    __shared__ float s_x[H2];
    int t = threadIdx.x;
    float4* s_x4 = (float4*)s_x;
    const float4* x4 = (const float4*)(ws + WS_L2);
    for (int k = t; k < H2 / 4; k += 256) s_x4[k] = x4[k];
    __syncthreads();
    int lane = t & 63, w = t >> 6;
    int i = blockIdx.x * 4 + w;
    const float4* wr = (const float4*)(W3 + (size_t)i * H2);
    float acc = 0.f;
    for (int k = lane; k < H2 / 4; k += 64) {
        float4 x = s_x4[k];
        float4 a = wr[k];
        acc += a.x * x.x + a.y * x.y + a.z * x.z + a.w * x.w;
    }
    acc = wave_sum(acc);
    if (lane == 0) ws[WS_KG + i] = acc + b3[i];
}

// ---- kernel 6: out = m1x_prior + kg @ dy ----
__global__ void k_out(const float* __restrict__ ws, float* __restrict__ out) {
    int t = threadIdx.x;
    if (t < M_DIM) {
        float acc = ws[WS_PRIOR + t];
        #pragma unroll
        for (int n = 0; n < N_DIM; ++n)
            acc += ws[WS_KG + t * N_DIM + n] * ws[WS_DY + n];
        out[t] = acc;
    }
}

extern "C" void kernel_launch(void* const* d_in, const int* in_sizes, int n_in,
                              void* d_out, int out_size, void* d_ws, size_t ws_size,
                              hipStream_t stream) {
    const float* yt        = (const float*)d_in[0];
    const float* F         = (const float*)d_in[1];
    const float* Hm        = (const float*)d_in[2];
    const float* post      = (const float*)d_in[3];
    const float* prior_old = (const float*)d_in[4];
    const float* hn        = (const float*)d_in[5];
    const float* W1        = (const float*)d_in[6];
    const float* b1        = (const float*)d_in[7];
    const float* Wih       = (const float*)d_in[8];
    const float* Whh       = (const float*)d_in[9];
    const float* bih       = (const float*)d_in[10];
    const float* bhh       = (const float*)d_in[11];
    const float* W2        = (const float*)d_in[12];
    const float* b2        = (const float*)d_in[13];
    const float* W3        = (const float*)d_in[14];
    const float* b3        = (const float*)d_in[15];
    float* out = (float*)d_out;
    float* ws  = (float*)d_ws;

    k_head<<<1, 64, 0, stream>>>(yt, F, Hm, post, prior_old, ws);
    k_l1 <<<H1 / 4, 256, 0, stream>>>(W1, b1, ws);
    k_gru<<<HID / 4, 256, 0, stream>>>(Wih, Whh, bih, bhh, hn, ws);
    k_l2 <<<H2 / 4, 256, 0, stream>>>(W2, b2, ws);
    k_kg <<<DOUT / 4, 256, 0, stream>>>(W3, b3, ws);
    k_out<<<1, 64, 0, stream>>>(ws, out);
}

// Round 2
// 178.645 us; speedup vs baseline: 1.0819x; 1.0819x over previous
//
#include <hip/hip_runtime.h>
#include <math.h>

#define M_DIM 24
#define N_DIM 12
#define H1    2880
#define HID   7200
#define H2    1152
#define DOUT  288
#define KGIN  (M_DIM + N_DIM)

// workspace layout (float offsets)
#define WS_PRIOR 0      // [24]
#define WS_DY    96     // [12]
#define WS_L1    128    // [2880]
#define WS_HNEW  3072   // [7200]
#define WS_L2    10304  // [1152]

__device__ __forceinline__ float wave_sum(float v) {
    #pragma unroll
    for (int o = 32; o; o >>= 1) v += __shfl_xor(v, o);
    return v;
}

// ---- kernel 1: head (redundant per block) + l1 = relu(W1 @ kg_in + b1) ----
// 4 rows of W1 per block (wave per row). Head compute (~600 FLOPs on L2-cached
// inputs) is redundant per block; block 0 also publishes prior/dy to ws.
__global__ __launch_bounds__(256) void k_l1h(
        const float* __restrict__ yt, const float* __restrict__ F,
        const float* __restrict__ Hm, const float* __restrict__ post,
        const float* __restrict__ prior_old,
        const float* __restrict__ W1, const float* __restrict__ b1,
        float* __restrict__ ws) {
    __shared__ float s_prior[M_DIM];
    __shared__ float s_m1y[N_DIM];
    __shared__ float s_x[KGIN];
    __shared__ float s_dy[N_DIM];
    int t = threadIdx.x, lane = t & 63, w = t >> 6;

    if (t < M_DIM) {
        float acc = 0.f;
        #pragma unroll
        for (int j = 0; j < M_DIM; ++j) acc += F[t * M_DIM + j] * post[j];
        s_prior[t] = acc;
    }
    __syncthreads();
    if (t < N_DIM) {
        float acc = 0.f;
        #pragma unroll
        for (int j = 0; j < M_DIM; ++j) acc += Hm[t * M_DIM + j] * s_prior[j];
        s_m1y[t] = acc;
    }
    __syncthreads();
    if (w == 0) {  // wave 0 does the normalizations (shfl-based)
        float vx = 0.f;
        if (lane < M_DIM) vx = post[lane] - prior_old[lane];
        float nx = fmaxf(sqrtf(wave_sum(vx * vx)), 1e-12f);
        float vy = 0.f;
        if (lane < N_DIM) vy = yt[lane] - s_m1y[lane];
        float ny = fmaxf(sqrtf(wave_sum(vy * vy)), 1e-12f);
        if (lane < N_DIM) { s_x[lane] = vy / ny; s_dy[lane] = vy; }
        if (lane < M_DIM) s_x[N_DIM + lane] = vx / nx;
    }
    __syncthreads();

    if (blockIdx.x == 0) {
        if (t < M_DIM) ws[WS_PRIOR + t] = s_prior[t];
        if (t < N_DIM) ws[WS_DY + t] = s_dy[t];
    }

    int i = blockIdx.x * 4 + w;
    float acc = (lane < KGIN) ? W1[(size_t)i * KGIN + lane] * s_x[lane] : 0.f;
    acc = wave_sum(acc);
    if (lane == 0) ws[WS_L1 + i] = fmaxf(acc + b1[i], 0.f);
}

// ---- kernel 2: GRU cell, one wave per output element, no LDS ----
// x-vectors (l1: 11.5 KB, hn: 28.8 KB) are L2-resident; staging them in LDS
// capped occupancy at 3 blocks/CU. Read through cache instead.
__global__ __launch_bounds__(256, 4) void k_gru(
        const float* __restrict__ Wih, const float* __restrict__ Whh,
        const float* __restrict__ bih, const float* __restrict__ bhh,
        const float* __restrict__ hn, float* __restrict__ ws) {
    int t = threadIdx.x, lane = t & 63, w = t >> 6;
    int i = blockIdx.x * 4 + w;

    const float4* x1 = (const float4*)(ws + WS_L1);
    const float4* xh = (const float4*)hn;

    const float4* wr = (const float4*)(Wih + (size_t)i * H1);
    const float4* wz = (const float4*)(Wih + (size_t)(i + HID) * H1);
    const float4* wn = (const float4*)(Wih + (size_t)(i + 2 * HID) * H1);
    float ar = 0.f, az = 0.f, an = 0.f;
    #pragma unroll 2
    for (int k = lane; k < H1 / 4; k += 64) {
        float4 x = x1[k];
        float4 a = wr[k], b = wz[k], c = wn[k];
        ar += a.x * x.x + a.y * x.y + a.z * x.z + a.w * x.w;
        az += b.x * x.x + b.y * x.y + b.z * x.z + b.w * x.w;
        an += c.x * x.x + c.y * x.y + c.z * x.z + c.w * x.w;
    }

    const float4* ur = (const float4*)(Whh + (size_t)i * HID);
    const float4* uz = (const float4*)(Whh + (size_t)(i + HID) * HID);
    const float4* un = (const float4*)(Whh + (size_t)(i + 2 * HID) * HID);
    float hr = 0.f, hz = 0.f, hh = 0.f;
    #pragma unroll 2
    for (int k = lane; k < HID / 4; k += 64) {
        float4 x = xh[k];
        float4 a = ur[k], b = uz[k], c = un[k];
        hr += a.x * x.x + a.y * x.y + a.z * x.z + a.w * x.w;
        hz += b.x * x.x + b.y * x.y + b.z * x.z + b.w * x.w;
        hh += c.x * x.x + c.y * x.y + c.z * x.z + c.w * x.w;
    }

    ar = wave_sum(ar); az = wave_sum(az); an = wave_sum(an);
    hr = wave_sum(hr); hz = wave_sum(hz); hh = wave_sum(hh);

    if (lane == 0) {
        float gr = ar + bih[i] + hr + bhh[i];
        float gz = az + bih[i + HID] + hz + bhh[i + HID];
        float r = 1.f / (1.f + expf(-gr));
        float z = 1.f / (1.f + expf(-gz));
        float n = tanhf(an + bih[i + 2 * HID] + r * (hh + bhh[i + 2 * HID]));
        ws[WS_HNEW + i] = (1.f - z) * n + z * hn[i];
    }
}

// ---- kernel 3: l2 = relu(W2 @ h_new + b2), wave per row, no LDS ----
__global__ __launch_bounds__(256, 4) void k_l2(
        const float* __restrict__ W2, const float* __restrict__ b2,
        float* __restrict__ ws) {
    int t = threadIdx.x, lane = t & 63, w = t >> 6;
    int i = blockIdx.x * 4 + w;
    const float4* x4 = (const float4*)(ws + WS_HNEW);
    const float4* wr = (const float4*)(W2 + (size_t)i * HID);
    float acc = 0.f;
    #pragma unroll 2
    for (int k = lane; k < HID / 4; k += 64) {
        float4 x = x4[k];
        float4 a = wr[k];
        acc += a.x * x.x + a.y * x.y + a.z * x.z + a.w * x.w;
    }
    acc = wave_sum(acc);
    if (lane == 0) ws[WS_L2 + i] = fmaxf(acc + b2[i], 0.f);
}

// ---- kernel 4: kg = W3 @ l2 + b3 fused with out = prior + kg @ dy ----
// one block per output row m; 12 waves, one per kg column.
__global__ __launch_bounds__(768) void k_kg_out(
        const float* __restrict__ W3, const float* __restrict__ b3,
        const float* __restrict__ ws, float* __restrict__ out) {
    __shared__ float s_kg[N_DIM];
    int m = blockIdx.x;
    int t = threadIdx.x, lane = t & 63, w = t >> 6;  // w: 0..11
    int row = m * N_DIM + w;
    const float4* wr = (const float4*)(W3 + (size_t)row * H2);
    const float4* x4 = (const float4*)(ws + WS_L2);
    float acc = 0.f;
    for (int k = lane; k < H2 / 4; k += 64) {
        float4 x = x4[k];
        float4 a = wr[k];
        acc += a.x * x.x + a.y * x.y + a.z * x.z + a.w * x.w;
    }
    acc = wave_sum(acc);
    if (lane == 0) s_kg[w] = acc + b3[row];
    __syncthreads();
    if (t == 0) {
        float a = ws[WS_PRIOR + m];
        #pragma unroll
        for (int n = 0; n < N_DIM; ++n) a += s_kg[n] * ws[WS_DY + n];
        out[m] = a;
    }
}

extern "C" void kernel_launch(void* const* d_in, const int* in_sizes, int n_in,
                              void* d_out, int out_size, void* d_ws, size_t ws_size,
                              hipStream_t stream) {
    const float* yt        = (const float*)d_in[0];
    const float* F         = (const float*)d_in[1];
    const float* Hm        = (const float*)d_in[2];
    const float* post      = (const float*)d_in[3];
    const float* prior_old = (const float*)d_in[4];
    const float* hn        = (const float*)d_in[5];
    const float* W1        = (const float*)d_in[6];
    const float* b1        = (const float*)d_in[7];
    const float* Wih       = (const float*)d_in[8];
    const float* Whh       = (const float*)d_in[9];
    const float* bih       = (const float*)d_in[10];
    const float* bhh       = (const float*)d_in[11];
    const float* W2        = (const float*)d_in[12];
    const float* b2        = (const float*)d_in[13];
    const float* W3        = (const float*)d_in[14];
    const float* b3        = (const float*)d_in[15];
    float* out = (float*)d_out;
    float* ws  = (float*)d_ws;

    k_l1h  <<<H1 / 4, 256, 0, stream>>>(yt, F, Hm, post, prior_old, W1, b1, ws);
    k_gru  <<<HID / 4, 256, 0, stream>>>(Wih, Whh, bih, bhh, hn, ws);
    k_l2   <<<H2 / 4, 256, 0, stream>>>(W2, b2, ws);
    k_kg_out<<<M_DIM, 768, 0, stream>>>(W3, b3, ws, out);
}